// Round 18
// baseline (61.217 us; speedup 1.0000x reference)
//
#include <hip/hip_runtime.h>
#include <math.h>

#define NCAND 75
#define NBT 8
#define NC 3
#define IMH 192
#define IMW 192
#define CROP 174
#define CH0 9
#define CW0 9
#define NPIX (CROP * CROP)          // 30276
#define CHW (IMH * IMW)             // 36864
#define IMG_STRIDE (NC * CHW)
#define DENOM 90828.0f              // NC * CROP * CROP
#define ROWS 6                      // crop rows per item (R15 chassis)
#define NCHUNK (CROP / ROWS)        // 29
#define NHW 25
#define NIR 3
#define SLABROWS 12                 // ih-specific window (validated R8-R17)
#define NTHREADS 384                // 6 waves: (half, column)
#define HALF_ROWS 3
#define SXY (96.0f / 95.5f)
#define NITEM (NHW * NBT * NCHUNK)  // 5800
#define NPBLK 512                   // persistent blocks: 2/CU (measured cap)

typedef float v2f __attribute__((ext_vector_type(2)));

// fp32 cos/sin of (1-ir) degrees (<=1 ulp vs device cosf/sinf; argmin safe)
__device__ __constant__ const float CR3[3] = {0.9998477f, 1.0f, 0.9998477f};
__device__ __constant__ const float SR3[3] = {0.017452406f, 0.0f, -0.017452406f};

// Bounds: rows [i0+ash+6, i0+ash+17] = 12 rows from ybase=i0+8-ih in [4,176];
// max staged row <= 187 < 192; x0 in [4,186], x1 <= 187. No masking.
// (validated on-device R8-R17, absmax 0.0)

// item e = (chunk*8 + im)*25 + hw  (hw fastest: consecutive items share the
// (im,chunk) source rows -> L2 hot, same as the old 3-D grid dispatch order)
__device__ __forceinline__ void stage_slab(const float* __restrict__ img,
                                           int e, float* dst, int tid) {
    const int hw    = e % NHW;
    const int g     = e / NHW;
    const int im    = g % NBT;
    const int chunk = g / NBT;
    const int ih    = hw / 5;
    const int ybase = chunk * ROWS + 8 - ih;
    const float4* __restrict__ src4 = (const float4*)(img + im * IMG_STRIDE);
    const int r0 = tid / 48;          // 0..7
    const int c4 = tid - r0 * 48;     // 0..47
#pragma unroll
    for (int s = 0; s < 5; ++s) {
        const int r = r0 + s * 8;     // planar row c*12+rr, step 8
        if (r < NC * SLABROWS) {
            const int csel = (r >= 12) + (r >= 24);
            const int rr   = r - csel * 12;
            const float4* gp = src4 + csel * (CHW / 4) + (ybase + rr) * 48 + c4;
            char* l = ((char*)dst) + (size_t)(r * 48 + c4) * 16;
            __builtin_amdgcn_global_load_lds(
                (const __attribute__((address_space(1))) void*)gp,
                (__attribute__((address_space(3))) void*)l, 16, 0, 0);
        }
    }
}

// --- kernel 1: persistent blocks, double-buffered slab pipeline ------------
// Per item: barrier -> issue NEXT item's DMA -> refv+compute current (hides
// DMA latency) -> barrier (prefetch already landed) -> reduce. The DMA drain
// that cost ~1us/block in R15-R17 now overlaps ~2.5us of compute.
__global__ __launch_bounds__(NTHREADS, 3) void sad_lds_kernel(
        const float* __restrict__ img,
        const float* __restrict__ ref,
        float* __restrict__ part) {
    const int bid = blockIdx.x;
    const int tid = threadIdx.x;
    const int j     = tid % 192;          // crop column
    const int half  = tid / 192;          // 0..1
    const int rbase = half * HALF_ROWS;
    const int wid   = tid >> 6;
    const int lane  = tid & 63;

    __shared__ float slabA[NC * SLABROWS * IMW];  // 27648 B
    __shared__ float slabB[NC * SLABROWS * IMW];  // 27648 B
    __shared__ float overlay[NIR][NTHREADS];      // 4608 B

    float* cur = slabA;
    float* nxt = slabB;

    stage_slab(img, bid, cur, tid);       // prologue stage (drained at first barrier)

    for (int e = bid; e < NITEM; e += NPBLK) {
        __syncthreads();                  // cur's DMA complete; overlay reuse safe

        const int en = e + NPBLK;
        if (en < NITEM) stage_slab(img, en, nxt, tid);   // async prefetch

        // ---- decompose item ----
        const int hw    = e % NHW;
        const int g     = e / NHW;
        const int im    = g % NBT;
        const int chunk = g / NBT;
        const int ih = hw / 5;
        const int iw = hw % 5;
        const int i0    = chunk * ROWS;
        const int ybase = i0 + 8 - ih;

        float acc[NIR];
#pragma unroll
        for (int k = 0; k < NIR; ++k) acc[k] = 0.0f;

        if (j < CROP) {
            // refv loads issue here; DMA for `nxt` is already in flight
            float refv[HALF_ROWS][NC];
            const float* __restrict__ rb = ref + im * IMG_STRIDE;
#pragma unroll
            for (int r = 0; r < HALF_ROWS; ++r)
#pragma unroll
                for (int c = 0; c < NC; ++c)
                    refv[r][c] = rb[c * CHW + (CH0 + i0 + rbase + r) * IMW + (CW0 + j)];

            const float jf  = (float)j;
            const float ash = (float)(2 - ih);
            const float asw = (float)(2 - iw);
            const float c0  = ((float)CW0 + asw) - 95.5f;
            const float t2_0 = ((float)(CH0 + i0 + rbase) + ash) - 95.5f;

            // ---- k = 0, 2 (rotated): packed transform + packed bilinear ----
#pragma unroll
            for (int kk = 0; kk < 2; ++kk) {
                const int k = kk * 2;
                const float cr = CR3[k];
                const float sr = SR3[k];
                const v2f   s2  = { cr * SXY, sr * SXY };
                const v2f   d2  = { -sr * SXY, cr * SXY };

                v2f b2 = { (cr * c0 - sr * t2_0) * SXY + 95.5f,
                           (sr * c0 + cr * t2_0) * SXY + (95.5f - (float)ybase) };
                const v2f jf2 = { jf, jf };

#pragma unroll
                for (int r = 0; r < HALF_ROWS; ++r) {
                    const v2f xy = jf2 * s2 + b2;       // pk_fma: {x, yl}
                    const int x0 = (int)xy.x;           // trunc == floor (x>0)
                    const int y0 = (int)xy.y;
                    const v2f xy0f = { (float)x0, (float)y0 };
                    const v2f w2 = xy - xy0f;
                    const v2f om2 = (v2f){1.0f, 1.0f} - w2;

                    const v2f hx = { om2.x, w2.x };
                    const v2f wtop = hx * om2.y;        // {w00, w10}
                    const v2f wbot = hx * w2.y;         // {w01, w11}

                    const float* __restrict__ p0 = &cur[y0 * IMW + x0];
                    const v2f tp0 = { p0[0],               p0[1] };
                    const v2f bt0 = { p0[IMW],             p0[IMW + 1] };
                    const v2f tp1 = { p0[SLABROWS*IMW],    p0[SLABROWS*IMW + 1] };
                    const v2f bt1 = { p0[SLABROWS*IMW+IMW], p0[SLABROWS*IMW+IMW+1] };
                    const v2f tp2 = { p0[2*SLABROWS*IMW],  p0[2*SLABROWS*IMW + 1] };
                    const v2f bt2 = { p0[2*SLABROWS*IMW+IMW], p0[2*SLABROWS*IMW+IMW+1] };

                    const v2f s0 = wtop * tp0 + wbot * bt0;
                    const v2f s1 = wtop * tp1 + wbot * bt1;
                    const v2f s2c = wtop * tp2 + wbot * bt2;
                    acc[k] += fabsf((s0.x + s0.y) - refv[r][0]);
                    acc[k] += fabsf((s1.x + s1.y) - refv[r][1]);
                    acc[k] += fabsf((s2c.x + s2c.y) - refv[r][2]);

                    b2 = b2 + d2;
                }
            }

            // ---- k = 1 (sr == 0 exactly): x/wx/x0 row-invariant ----
            {
                const float x  = fmaf(jf, SXY, c0 * SXY + 95.5f);
                const int x0 = (int)x;
                const float wx = x - (float)x0;
                const float omwx = 1.0f - wx;
                float yb = t2_0 * SXY + (95.5f - (float)ybase);

#pragma unroll
                for (int r = 0; r < HALF_ROWS; ++r) {
                    const int y0 = (int)yb;
                    const float wy = yb - (float)y0;
                    const float omwy = 1.0f - wy;
                    const v2f hx = { omwx, wx };
                    const v2f wtop = hx * omwy;
                    const v2f wbot = hx * wy;

                    const float* __restrict__ p0 = &cur[y0 * IMW + x0];
                    const v2f tp0 = { p0[0],               p0[1] };
                    const v2f bt0 = { p0[IMW],             p0[IMW + 1] };
                    const v2f tp1 = { p0[SLABROWS*IMW],    p0[SLABROWS*IMW + 1] };
                    const v2f bt1 = { p0[SLABROWS*IMW+IMW], p0[SLABROWS*IMW+IMW+1] };
                    const v2f tp2 = { p0[2*SLABROWS*IMW],  p0[2*SLABROWS*IMW + 1] };
                    const v2f bt2 = { p0[2*SLABROWS*IMW+IMW], p0[2*SLABROWS*IMW+IMW+1] };

                    const v2f s0 = wtop * tp0 + wbot * bt0;
                    const v2f s1 = wtop * tp1 + wbot * bt1;
                    const v2f s2c = wtop * tp2 + wbot * bt2;
                    acc[1] += fabsf((s0.x + s0.y) - refv[r][0]);
                    acc[1] += fabsf((s1.x + s1.y) - refv[r][1]);
                    acc[1] += fabsf((s2c.x + s2c.y) - refv[r][2]);

                    yb += SXY;
                }
            }
        }

        // ---- reduce: overlay + 3-wave tree ----
#pragma unroll
        for (int k = 0; k < NIR; ++k)
            overlay[k][tid] = acc[k];
        __syncthreads();                  // also drains nxt prefetch (landed)

        if (wid < NIR) {                  // wave w reduces candidate ir=w
            float a = 0.0f;
#pragma unroll
            for (int s = 0; s < 6; ++s)
                a += overlay[wid][lane + 64 * s];
#pragma unroll
            for (int off = 32; off > 0; off >>= 1) a += __shfl_down(a, off, 64);
            if (lane == 0) {
                const int cand = hw * 3 + wid;
                part[(cand * NCHUNK + chunk) * NBT + im] = a;
            }
        }

        float* t = cur; cur = nxt; nxt = t;   // ping-pong
    }
}

// --- kernel 2: reduce chunks -> sad, then per-image argmin -----------------
__global__ __launch_bounds__(640) void finalize_ws(const float* __restrict__ part,
                                                   float* __restrict__ out) {
    __shared__ float sads[NCAND * NBT];
    const int t = threadIdx.x;
    if (t < NCAND * NBT) {
        const int cand = t / NBT;
        const int im   = t % NBT;
        float ssum = 0.0f;
        const float* p = part + cand * NCHUNK * NBT + im;
        for (int ch = 0; ch < NCHUNK; ++ch) ssum += p[ch * NBT];
        const float sv = ssum / DENOM;
        sads[t] = sv;
        out[t] = sv;
    }
    __syncthreads();
    if (t < NBT) {
        float best = sads[t];
        int bi = 0;
        for (int c2 = 1; c2 < NCAND; ++c2) {
            const float v = sads[c2 * NBT + t];
            if (v < best) { best = v; bi = c2; }   // strict <: first-min tie-break
        }
        const int i0 = bi / 15;
        const int r  = bi % 15;
        const int i1 = r / 3;
        const int i2 = r % 3;
        out[600 + 0 * NBT + t] = (float)i0;
        out[600 + 1 * NBT + t] = (float)i1;
        out[600 + 2 * NBT + t] = (float)i2;
        out[600 + 3 * NBT + t] = 0.0f;
    }
}

// ---------------- fallback (tiny ws): direct per-(cand,img) path -----------
__global__ __launch_bounds__(256) void sad_direct_kernel(const float* __restrict__ img,
                                                         const float* __restrict__ ref,
                                                         float* __restrict__ out) {
    const int ci  = blockIdx.x;
    const int cand = ci / NBT;
    const int im   = ci % NBT;
    const int ih  = cand / 15;
    const int rem = cand % 15;
    const int iw  = rem / 3;
    const int ir  = rem % 3;
    const float ash  = (float)(2 - ih);
    const float asw  = (float)(2 - iw);
    const float cr = CR3[ir];
    const float sr = SR3[ir];
    const float* ib = img + im * IMG_STRIDE;
    const float* rb = ref + im * IMG_STRIDE;
    float acc = 0.0f;
    for (int p = (int)threadIdx.x; p < NPIX; p += 256) {
        const int i = p / CROP;
        const int j = p - i * CROP;
        const float t1 = ((float)(CW0 + j) + asw) - 95.5f;
        const float t2 = ((float)(CH0 + i) + ash) - 95.5f;
        const float awr = cr * t1 - sr * t2;
        const float ahr = sr * t1 + cr * t2;
        const float x = awr * SXY + 95.5f;
        const float y = ahr * SXY + 95.5f;
        const float x0f = floorf(x);
        const float y0f = floorf(y);
        const float wx = x - x0f;
        const float wy = y - y0f;
        const int x0 = (int)x0f, y0 = (int)y0f;
        const float omwx = 1.0f - wx;
        const float omwy = 1.0f - wy;
        const float w00 = omwx * omwy;
        const float w10 = wx * omwy;
        const float w01 = omwx * wy;
        const float w11 = wx * wy;
        const int a00 = y0 * IMW + x0;
        const int ra  = (CH0 + i) * IMW + (CW0 + j);
#pragma unroll
        for (int c = 0; c < NC; ++c) {
            const float* cb = ib + c * CHW + a00;
            const float v = w00 * cb[0] + w10 * cb[1] +
                            w01 * cb[IMW] + w11 * cb[IMW + 1];
            acc += fabsf(v - rb[c * CHW + ra]);
        }
    }
#pragma unroll
    for (int off = 32; off > 0; off >>= 1) acc += __shfl_down(acc, off, 64);
    __shared__ float wsum[4];
    const int lane = threadIdx.x & 63;
    const int wid  = threadIdx.x >> 6;
    if (lane == 0) wsum[wid] = acc;
    __syncthreads();
    if (threadIdx.x == 0)
        out[ci] = (wsum[0] + wsum[1] + wsum[2] + wsum[3]) / DENOM;
}

__global__ __launch_bounds__(64) void finalize_direct(float* __restrict__ out) {
    const int t = threadIdx.x;
    if (t < NBT) {
        float best = out[t];
        int bi = 0;
        for (int c2 = 1; c2 < NCAND; ++c2) {
            const float v = out[c2 * NBT + t];
            if (v < best) { best = v; bi = c2; }
        }
        const int i0 = bi / 15;
        const int r  = bi % 15;
        const int i1 = r / 3;
        const int i2 = r % 3;
        out[600 + 0 * NBT + t] = (float)i0;
        out[600 + 1 * NBT + t] = (float)i1;
        out[600 + 2 * NBT + t] = (float)i2;
        out[600 + 3 * NBT + t] = 0.0f;
    }
}

extern "C" void kernel_launch(void* const* d_in, const int* in_sizes, int n_in,
                              void* d_out, int out_size, void* d_ws, size_t ws_size,
                              hipStream_t stream) {
    const float* img = (const float*)d_in[0];
    const float* ref = (const float*)d_in[1];
    float* out = (float*)d_out;

    if (ws_size >= (size_t)(NCAND * NCHUNK * NBT * sizeof(float))) {
        float* part = (float*)d_ws;
        hipLaunchKernelGGL(sad_lds_kernel, dim3(NPBLK), dim3(NTHREADS),
                           0, stream, img, ref, part);
        hipLaunchKernelGGL(finalize_ws, dim3(1), dim3(640), 0, stream, part, out);
    } else {
        hipLaunchKernelGGL(sad_direct_kernel, dim3(NCAND * NBT), dim3(256),
                           0, stream, img, ref, out);
        hipLaunchKernelGGL(finalize_direct, dim3(1), dim3(64), 0, stream, out);
    }
}

// Round 19
// 39.220 us; speedup vs baseline: 1.5608x; 1.5608x over previous
//
#include <hip/hip_runtime.h>
#include <math.h>

#define NCAND 75
#define NBT 8
#define NC 3
#define IMH 192
#define IMW 192
#define CROP 174
#define CH0 9
#define CW0 9
#define NPIX (CROP * CROP)          // 30276
#define CHW (IMH * IMW)             // 36864
#define IMG_STRIDE (NC * CHW)
#define DENOM 90828.0f              // NC * CROP * CROP
#define ROWS 6                      // crop rows per block (best chassis, R15/R17)
#define NCHUNK (CROP / ROWS)        // 29
#define NHW 25                      // (ih,iw) shift combos -> grid dim
#define NIR 3                       // rotations in-register (compile-time)
#define SLABROWS 12                 // ih-specific window (validated R8-R18)
#define NTHREADS 384                // 6 waves: (half, column)
#define HALF_ROWS 3
#define SXY (96.0f / 95.5f)         // x = awr*SXY + 95.5 (exact algebra of ref chain)
#define RSTRIDE 392                 // overlay plane stride (floats)

typedef float v2f __attribute__((ext_vector_type(2)));

// fp32 cos/sin of (1-ir) degrees, ir=0,1,2  (<=1 ulp vs device cosf/sinf; SAD
// perturbation ~1e-7, threshold 8e-2, inter-candidate gaps ~1e-1 -> argmin safe)
__device__ __constant__ const float CR3[3] = {0.9998477f, 1.0f, 0.9998477f};
__device__ __constant__ const float SR3[3] = {0.017452406f, 0.0f, -0.017452406f};

// Bounds (ih fixed per block): rows [i0+ash+6, i0+ash+17]: 12 rows,
// ybase = i0+8-ih in [4,176]; max staged row <= 187 < 192. x0 in [4,186],
// x1 <= 187. No masking needed. (validated on-device R8-R18, absmax 0.0)

// --- kernel 1: R17 configuration (measured optimum, 39.26 us) --------------
// Session model (R4-R18): scheduler caps residency at ~2 blocks/CU for any
// LDS <= ~40KB (1 block above ~55KB) -> occupancy is NOT a lever; dur =
// ~26us VALU-issue busy at 12 waves/CU + ~13us unpipelinable drain/launch.
// Double-buffer (R18), taller chunks (R16), in-block loops (R8/R13), more
// waves (R14), XCD swizzle (R9) all regress. Wins: LDS slab (R4), DMA
// staging (R11), overlay reduce (R12), packed-f32 + trunc-floor (R15/R17).
__global__ __launch_bounds__(NTHREADS, 6) void sad_lds_kernel(
        const float* __restrict__ img,
        const float* __restrict__ ref,
        float* __restrict__ part) {
    const int hw    = blockIdx.x;         // 0..24 (fastest: shares slab in L2)
    const int im    = blockIdx.y;         // 0..7
    const int chunk = blockIdx.z;         // 0..28
    const int ih = hw / 5;
    const int iw = hw % 5;

    const int i0    = chunk * ROWS;
    const int ybase = i0 + 8 - ih;        // = i0 + ash + 6
    const int tid   = threadIdx.x;
    const int j     = tid % 192;          // crop column
    const int half  = tid / 192;          // 0..1
    const int rbase = half * HALF_ROWS;   // rows rbase..rbase+2 of the chunk

    __shared__ float slab[NC * SLABROWS * IMW];   // 27648 B; reused for reduce

    // ---- stage slab: 1728 float4 via async global->LDS DMA ----
    {
        const float4* __restrict__ src4 = (const float4*)(img + im * IMG_STRIDE);
        const int r0 = tid / 48;          // 0..7
        const int c4 = tid - r0 * 48;     // 0..47
#pragma unroll
        for (int s = 0; s < 5; ++s) {
            const int r = r0 + s * 8;     // planar row c*12+rr, step 8
            if (r < NC * SLABROWS) {
                const int csel = (r >= 12) + (r >= 24);
                const int rr   = r - csel * 12;
                const float4* g = src4 + csel * (CHW / 4) + (ybase + rr) * 48 + c4;
                char* l = ((char*)slab) + (size_t)(r * 48 + c4) * 16;
                __builtin_amdgcn_global_load_lds(
                    (const __attribute__((address_space(1))) void*)g,
                    (__attribute__((address_space(3))) void*)l, 16, 0, 0);
            }
        }
    }

    // ---- ref pixels (issued while DMA in flight), kept in registers ----
    float refv[HALF_ROWS][NC];
    if (j < CROP) {
        const float* __restrict__ rb = ref + im * IMG_STRIDE;
#pragma unroll
        for (int r = 0; r < HALF_ROWS; ++r)
#pragma unroll
            for (int c = 0; c < NC; ++c)
                refv[r][c] = rb[c * CHW + (CH0 + i0 + rbase + r) * IMW + (CW0 + j)];
    }
    __syncthreads();                      // drains vmcnt (DMA + refv) + barrier

    float acc[NIR];
#pragma unroll
    for (int k = 0; k < NIR; ++k) acc[k] = 0.0f;

    if (j < CROP) {
        const float jf  = (float)j;
        const float ash = (float)(2 - ih);
        const float asw = (float)(2 - iw);
        const float c0  = ((float)CW0 + asw) - 95.5f;
        const float t2_0 = ((float)(CH0 + i0 + rbase) + ash) - 95.5f;

        // ---- k = 0, 2 (rotated): packed {x,y} transform + packed bilinear --
#pragma unroll
        for (int kk = 0; kk < 2; ++kk) {
            const int k = kk * 2;                       // 0 or 2, compile-time
            const float cr = CR3[k];
            const float sr = SR3[k];
            const v2f   s2  = { cr * SXY, sr * SXY };   // {xs, ys}
            const v2f   d2  = { -sr * SXY, cr * SXY };  // {dxb, dyb}

            v2f b2 = { (cr * c0 - sr * t2_0) * SXY + 95.5f,
                       (sr * c0 + cr * t2_0) * SXY + (95.5f - (float)ybase) };
            const v2f jf2 = { jf, jf };

#pragma unroll
            for (int r = 0; r < HALF_ROWS; ++r) {
                const v2f xy = jf2 * s2 + b2;           // pk_fma: {x, yl}
                const int x0 = (int)xy.x;               // trunc == floor (x>0)
                const int y0 = (int)xy.y;
                const v2f xy0f = { (float)x0, (float)y0 };
                const v2f w2 = xy - xy0f;               // pk_sub: {wx, wy}
                const v2f om2 = (v2f){1.0f, 1.0f} - w2; // {omwx, omwy}

                const v2f hx = { om2.x, w2.x };         // {omwx, wx}
                const v2f wtop = hx * om2.y;            // {w00, w10}
                const v2f wbot = hx * w2.y;             // {w01, w11}

                const float* __restrict__ p0 = &slab[y0 * IMW + x0];
                // each {.,.} pair is one ds_read2_b32 -> consecutive VGPRs
                const v2f tp0 = { p0[0],               p0[1] };
                const v2f bt0 = { p0[IMW],             p0[IMW + 1] };
                const v2f tp1 = { p0[SLABROWS*IMW],    p0[SLABROWS*IMW + 1] };
                const v2f bt1 = { p0[SLABROWS*IMW+IMW], p0[SLABROWS*IMW+IMW+1] };
                const v2f tp2 = { p0[2*SLABROWS*IMW],  p0[2*SLABROWS*IMW + 1] };
                const v2f bt2 = { p0[2*SLABROWS*IMW+IMW], p0[2*SLABROWS*IMW+IMW+1] };

                const v2f s0 = wtop * tp0 + wbot * bt0;   // pk_mul + pk_fma
                const v2f s1 = wtop * tp1 + wbot * bt1;
                const v2f s2c = wtop * tp2 + wbot * bt2;
                acc[k] += fabsf((s0.x + s0.y) - refv[r][0]);
                acc[k] += fabsf((s1.x + s1.y) - refv[r][1]);
                acc[k] += fabsf((s2c.x + s2c.y) - refv[r][2]);

                b2 = b2 + d2;                           // pk_add
            }
        }

        // ---- k = 1 (sr == 0 exactly): x/wx/x0 row-invariant ----
        {
            const float x  = fmaf(jf, SXY, c0 * SXY + 95.5f);
            const int x0 = (int)x;
            const float wx = x - (float)x0;
            const float omwx = 1.0f - wx;
            float yb = t2_0 * SXY + (95.5f - (float)ybase);

#pragma unroll
            for (int r = 0; r < HALF_ROWS; ++r) {
                const int y0 = (int)yb;
                const float wy = yb - (float)y0;
                const float omwy = 1.0f - wy;
                const v2f hx = { omwx, wx };
                const v2f wtop = hx * omwy;             // {w00, w10}
                const v2f wbot = hx * wy;               // {w01, w11}

                const float* __restrict__ p0 = &slab[y0 * IMW + x0];
                const v2f tp0 = { p0[0],               p0[1] };
                const v2f bt0 = { p0[IMW],             p0[IMW + 1] };
                const v2f tp1 = { p0[SLABROWS*IMW],    p0[SLABROWS*IMW + 1] };
                const v2f bt1 = { p0[SLABROWS*IMW+IMW], p0[SLABROWS*IMW+IMW+1] };
                const v2f tp2 = { p0[2*SLABROWS*IMW],  p0[2*SLABROWS*IMW + 1] };
                const v2f bt2 = { p0[2*SLABROWS*IMW+IMW], p0[2*SLABROWS*IMW+IMW+1] };

                const v2f s0 = wtop * tp0 + wbot * bt0;
                const v2f s1 = wtop * tp1 + wbot * bt1;
                const v2f s2c = wtop * tp2 + wbot * bt2;
                acc[1] += fabsf((s0.x + s0.y) - refv[r][0]);
                acc[1] += fabsf((s1.x + s1.y) - refv[r][1]);
                acc[1] += fabsf((s2c.x + s2c.y) - refv[r][2]);

                yb += SXY;
            }
        }
    }

    // ---- reduce: overlay partials in slab (dead now), 3-wave tree ----
    __syncthreads();                      // all slab reads done
    float* __restrict__ overlay = slab;   // 3 planes of RSTRIDE floats
#pragma unroll
    for (int k = 0; k < NIR; ++k)
        overlay[k * RSTRIDE + tid] = acc[k];
    __syncthreads();

    const int wid  = tid >> 6;
    const int lane = tid & 63;
    if (wid < NIR) {                      // wave w reduces candidate ir=w
        float a = 0.0f;
#pragma unroll
        for (int s = 0; s < 6; ++s)
            a += overlay[wid * RSTRIDE + lane + 64 * s];
#pragma unroll
        for (int off = 32; off > 0; off >>= 1) a += __shfl_down(a, off, 64);
        if (lane == 0) {
            const int cand = hw * 3 + wid;   // = (ih*5+iw)*3+ir: ref order
            part[(cand * NCHUNK + chunk) * NBT + im] = a;
        }
    }
}

// --- kernel 2: reduce chunks -> sad, then per-image argmin -----------------
__global__ __launch_bounds__(640) void finalize_ws(const float* __restrict__ part,
                                                   float* __restrict__ out) {
    __shared__ float sads[NCAND * NBT];
    const int t = threadIdx.x;
    if (t < NCAND * NBT) {
        const int cand = t / NBT;
        const int im   = t % NBT;
        float ssum = 0.0f;
        const float* p = part + cand * NCHUNK * NBT + im;
        for (int ch = 0; ch < NCHUNK; ++ch) ssum += p[ch * NBT];
        const float sv = ssum / DENOM;
        sads[t] = sv;
        out[t] = sv;
    }
    __syncthreads();
    if (t < NBT) {
        float best = sads[t];
        int bi = 0;
        for (int c2 = 1; c2 < NCAND; ++c2) {
            const float v = sads[c2 * NBT + t];
            if (v < best) { best = v; bi = c2; }   // strict <: first-min tie-break
        }
        const int i0 = bi / 15;
        const int r  = bi % 15;
        const int i1 = r / 3;
        const int i2 = r % 3;
        out[600 + 0 * NBT + t] = (float)i0;
        out[600 + 1 * NBT + t] = (float)i1;
        out[600 + 2 * NBT + t] = (float)i2;
        out[600 + 3 * NBT + t] = 0.0f;
    }
}

// ---------------- fallback (tiny ws): direct per-(cand,img) path -----------
__global__ __launch_bounds__(256) void sad_direct_kernel(const float* __restrict__ img,
                                                         const float* __restrict__ ref,
                                                         float* __restrict__ out) {
    const int ci  = blockIdx.x;
    const int cand = ci / NBT;
    const int im   = ci % NBT;
    const int ih  = cand / 15;
    const int rem = cand % 15;
    const int iw  = rem / 3;
    const int ir  = rem % 3;
    const float ash  = (float)(2 - ih);
    const float asw  = (float)(2 - iw);
    const float cr = CR3[ir];
    const float sr = SR3[ir];
    const float* ib = img + im * IMG_STRIDE;
    const float* rb = ref + im * IMG_STRIDE;
    float acc = 0.0f;
    for (int p = (int)threadIdx.x; p < NPIX; p += 256) {
        const int i = p / CROP;
        const int j = p - i * CROP;
        const float t1 = ((float)(CW0 + j) + asw) - 95.5f;
        const float t2 = ((float)(CH0 + i) + ash) - 95.5f;
        const float awr = cr * t1 - sr * t2;
        const float ahr = sr * t1 + cr * t2;
        const float x = awr * SXY + 95.5f;
        const float y = ahr * SXY + 95.5f;
        const float x0f = floorf(x);
        const float y0f = floorf(y);
        const float wx = x - x0f;
        const float wy = y - y0f;
        const int x0 = (int)x0f, y0 = (int)y0f;
        const float omwx = 1.0f - wx;
        const float omwy = 1.0f - wy;
        const float w00 = omwx * omwy;
        const float w10 = wx * omwy;
        const float w01 = omwx * wy;
        const float w11 = wx * wy;
        const int a00 = y0 * IMW + x0;
        const int ra  = (CH0 + i) * IMW + (CW0 + j);
#pragma unroll
        for (int c = 0; c < NC; ++c) {
            const float* cb = ib + c * CHW + a00;
            const float v = w00 * cb[0] + w10 * cb[1] +
                            w01 * cb[IMW] + w11 * cb[IMW + 1];
            acc += fabsf(v - rb[c * CHW + ra]);
        }
    }
#pragma unroll
    for (int off = 32; off > 0; off >>= 1) acc += __shfl_down(acc, off, 64);
    __shared__ float wsum[4];
    const int lane = threadIdx.x & 63;
    const int wid  = threadIdx.x >> 6;
    if (lane == 0) wsum[wid] = acc;
    __syncthreads();
    if (threadIdx.x == 0)
        out[ci] = (wsum[0] + wsum[1] + wsum[2] + wsum[3]) / DENOM;
}

__global__ __launch_bounds__(64) void finalize_direct(float* __restrict__ out) {
    const int t = threadIdx.x;
    if (t < NBT) {
        float best = out[t];
        int bi = 0;
        for (int c2 = 1; c2 < NCAND; ++c2) {
            const float v = out[c2 * NBT + t];
            if (v < best) { best = v; bi = c2; }
        }
        const int i0 = bi / 15;
        const int r  = bi % 15;
        const int i1 = r / 3;
        const int i2 = r % 3;
        out[600 + 0 * NBT + t] = (float)i0;
        out[600 + 1 * NBT + t] = (float)i1;
        out[600 + 2 * NBT + t] = (float)i2;
        out[600 + 3 * NBT + t] = 0.0f;
    }
}

extern "C" void kernel_launch(void* const* d_in, const int* in_sizes, int n_in,
                              void* d_out, int out_size, void* d_ws, size_t ws_size,
                              hipStream_t stream) {
    const float* img = (const float*)d_in[0];
    const float* ref = (const float*)d_in[1];
    float* out = (float*)d_out;

    if (ws_size >= (size_t)(NCAND * NCHUNK * NBT * sizeof(float))) {
        float* part = (float*)d_ws;
        hipLaunchKernelGGL(sad_lds_kernel, dim3(NHW, NBT, NCHUNK), dim3(NTHREADS),
                           0, stream, img, ref, part);
        hipLaunchKernelGGL(finalize_ws, dim3(1), dim3(640), 0, stream, part, out);
    } else {
        hipLaunchKernelGGL(sad_direct_kernel, dim3(NCAND * NBT), dim3(256),
                           0, stream, img, ref, out);
        hipLaunchKernelGGL(finalize_direct, dim3(1), dim3(64), 0, stream, out);
    }
}